// Round 7
// baseline (264.939 us; speedup 1.0000x reference)
//
#include <hip/hip_runtime.h>
#include <stdint.h>

#define D_MODEL 1024
#define NH      16
#define DKH     64
#define BATCH   2
#define SEQ     2048
#define M_TOK   (BATCH*SEQ)   // 4096

typedef __attribute__((ext_vector_type(8))) short bf16x8;   // 8 bf16 = 4 VGPRs
typedef __attribute__((ext_vector_type(4))) float f32x4;    // MFMA C/D

// fp32 -> bf16, round-to-nearest-even
__device__ __forceinline__ uint16_t f2b(float f) {
  uint32_t u = __builtin_bit_cast(uint32_t, f);
  return (uint16_t)((u + 0x7FFFu + ((u >> 16) & 1u)) >> 16);
}

// async global->LDS, 16B per lane. HW writes LDS at wave-uniform base + lane*16.
__device__ __forceinline__ void gl2lds16(const uint16_t* g, uint16_t* l) {
  __builtin_amdgcn_global_load_lds(
      (const __attribute__((address_space(1))) void*)g,
      (__attribute__((address_space(3))) void*)l, 16, 0, 0);
}

// ---- prep: convx (blocks 0..2047) + wtrans x4 (blocks 2048..6143), one launch ----
__global__ __launch_bounds__(256) void prep(
    const float* __restrict__ X, uint16_t* __restrict__ Xb,
    const float* __restrict__ W0, const float* __restrict__ W1,
    const float* __restrict__ W2, const float* __restrict__ W3,
    uint16_t* __restrict__ T0, uint16_t* __restrict__ T1,
    uint16_t* __restrict__ T2, uint16_t* __restrict__ T3) {
  const int bid = blockIdx.x;
  if (bid < 2048) {
    int i = (bid * 256 + threadIdx.x) * 8;
    float4 a = *(const float4*)(X + i);
    float4 b = *(const float4*)(X + i + 4);
    uint16_t tmp[8] = {f2b(a.x), f2b(a.y), f2b(a.z), f2b(a.w),
                       f2b(b.x), f2b(b.y), f2b(b.z), f2b(b.w)};
    *(uint4*)(Xb + i) = *(const uint4*)tmp;
  } else {
    __shared__ float tile[32][33];
    int r = bid - 2048;
    int z = r >> 10, tt = r & 1023;
    const float* W = (z == 0) ? W0 : (z == 1) ? W1 : (z == 2) ? W2 : W3;
    uint16_t*    T = (z == 0) ? T0 : (z == 1) ? T1 : (z == 2) ? T2 : T3;
    int k0 = (tt & 31) * 32, n0 = (tt >> 5) * 32;
    int t = threadIdx.x;
    int rr = t >> 3, c4 = (t & 7) * 4;
    float4 v = *(const float4*)(W + (size_t)(k0 + rr) * D_MODEL + n0 + c4);
    tile[rr][c4] = v.x; tile[rr][c4 + 1] = v.y;
    tile[rr][c4 + 2] = v.z; tile[rr][c4 + 3] = v.w;
    __syncthreads();
    uint16_t o[4] = {f2b(tile[c4][rr]), f2b(tile[c4 + 1][rr]),
                     f2b(tile[c4 + 2][rr]), f2b(tile[c4 + 3][rr])};
    *(uint2*)(T + (size_t)(n0 + rr) * D_MODEL + k0 + c4) = *(const uint2*)o;
  }
}

// ------ 128x128 bf16 MFMA GEMM core: double-buffered LDS, 1 barrier/K-step ------
template <bool SWAP>
__device__ __forceinline__ void gemm_core(const uint16_t* __restrict__ A,
                                          const uint16_t* __restrict__ BT,
                                          uint16_t* As, uint16_t* Bs,
                                          int m0, int n0, int kBeg, int kEnd,
                                          f32x4 (&acc)[4][4]) {
  const int t    = threadIdx.x;
  const int lane = t & 63;
  const int qi   = lane & 15, g = lane >> 4;
  const int wm   = (t >> 7) & 1;
  const int wn   = (t >> 6) & 1;
  const int srow = t >> 2;                       // staging row 0..63
  const int sc   = (t & 3) ^ ((t >> 3) & 3);     // swizzled global chunk
  const int wbase = t & 192;
  const int rch  = (g ^ ((qi >> 1) & 3)) * 8;    // swizzled read chunk (elems)

  const uint16_t* Ag = A  + (size_t)(m0 + srow) * D_MODEL + sc * 8;
  const uint16_t* Bg = BT + (size_t)(n0 + srow) * D_MODEL + sc * 8;

#pragma unroll
  for (int j = 0; j < 2; j++) {
    gl2lds16(Ag + (size_t)j * 64 * D_MODEL + kBeg, As + (j * 256 + wbase) * 8);
    gl2lds16(Bg + (size_t)j * 64 * D_MODEL + kBeg, Bs + (j * 256 + wbase) * 8);
  }

  int cur = 0;
  for (int k0 = kBeg; k0 < kEnd; k0 += 32) {
    __syncthreads();   // publishes buf[cur] (vmcnt drain) + reads of buf[cur^1] done
    int kn = k0 + 32;
    if (kn < kEnd) {
      int nb = (cur ^ 1) * 4096;
#pragma unroll
      for (int j = 0; j < 2; j++) {
        gl2lds16(Ag + (size_t)j * 64 * D_MODEL + kn, As + nb + (j * 256 + wbase) * 8);
        gl2lds16(Bg + (size_t)j * 64 * D_MODEL + kn, Bs + nb + (j * 256 + wbase) * 8);
      }
    }
    const uint16_t* Ab = As + cur * 4096;
    const uint16_t* Bb = Bs + cur * 4096;
    bf16x8 af[4], bf[4];
#pragma unroll
    for (int i = 0; i < 4; i++) {
      af[i] = *(const bf16x8*)(Ab + (wm * 64 + i * 16 + qi) * 32 + rch);
      bf[i] = *(const bf16x8*)(Bb + (wn * 64 + i * 16 + qi) * 32 + rch);
    }
#pragma unroll
    for (int i = 0; i < 4; i++)
#pragma unroll
      for (int j = 0; j < 4; j++)
        acc[i][j] = SWAP
          ? __builtin_amdgcn_mfma_f32_16x16x32_bf16(bf[j], af[i], acc[i][j], 0, 0, 0)
          : __builtin_amdgcn_mfma_f32_16x16x32_bf16(af[i], bf[j], acc[i][j], 0, 0, 0);
    cur ^= 1;
  }
}

// ---------------- fused QKV projection ----------------
// Grid (8 n, 32 m, 3 z): n fastest so consecutive blocks share one X m-tile (L2);
// z slowest so each 2MB weight stays L2-resident per phase.
__global__ __launch_bounds__(256) void qkv_gemm(
    const uint16_t* __restrict__ Xb,
    const uint16_t* __restrict__ WqT, const uint16_t* __restrict__ WkT,
    const uint16_t* __restrict__ WvT,
    const float* __restrict__ bq, const float* __restrict__ bk,
    const float* __restrict__ bv,
    uint16_t* __restrict__ Qo, uint16_t* __restrict__ Ko, uint16_t* __restrict__ Vt) {
  __shared__ __align__(16) uint16_t smem[17408];   // As/Bs dbuf (32KB) aliased with T
  uint16_t* As = smem;                             // [2][128][32]
  uint16_t* Bs = smem + 8192;                      // [2][128][32]
  uint16_t* T  = smem;                             // [128 ch][136] transpose buf (z==2)
  const int z = blockIdx.z;
  const uint16_t* BT  = (z == 0) ? WqT : (z == 1) ? WkT : WvT;
  const float*   bias = (z == 0) ? bq  : (z == 1) ? bk  : bv;
  const int m0 = blockIdx.y * 128, n0 = blockIdx.x * 128;
  const int lane = threadIdx.x & 63, qi = lane & 15, g = lane >> 4;
  const int wm = (threadIdx.x >> 7) & 1, wn = (threadIdx.x >> 6) & 1;
  const float l2e = 1.4426950408889634f * 0.125f;  // log2(e)/sqrt(dk), folded into Q

  const f32x4 ZERO = {0.f, 0.f, 0.f, 0.f};
  f32x4 acc[4][4];
#pragma unroll
  for (int i = 0; i < 4; i++)
#pragma unroll
    for (int j = 0; j < 4; j++) acc[i][j] = ZERO;

  if (z == 2) {
    gemm_core<false>(Xb, BT, As, Bs, m0, n0, 0, D_MODEL, acc);
    __syncthreads();  // all waves done with As/Bs before T overwrite
#pragma unroll
    for (int i = 0; i < 4; i++) {
      int tok = wm * 64 + i * 16 + g * 4;
#pragma unroll
      for (int j = 0; j < 4; j++) {
        int ch = wn * 64 + j * 16 + qi;
        float bb = bias[n0 + ch];
        uint32_t lo = (uint32_t)f2b(acc[i][j][0] + bb) | ((uint32_t)f2b(acc[i][j][1] + bb) << 16);
        uint32_t hi = (uint32_t)f2b(acc[i][j][2] + bb) | ((uint32_t)f2b(acc[i][j][3] + bb) << 16);
        uint2 pk = {lo, hi};
        *(uint2*)(T + ch * 136 + tok) = pk;
      }
    }
    __syncthreads();
    {
      int ch = threadIdx.x >> 1, sh = threadIdx.x & 1;
      const uint16_t* src = T + ch * 136 + sh * 64;
      int bidx = m0 >> 11;
      uint16_t* dst = Vt + ((size_t)(bidx * D_MODEL + n0 + ch)) * SEQ + (m0 & 2047) + sh * 64;
#pragma unroll
      for (int u = 0; u < 8; u++)
        *(uint4*)(dst + u * 8) = *(const uint4*)(src + u * 8);
    }
  } else {
    gemm_core<true>(Xb, BT, As, Bs, m0, n0, 0, D_MODEL, acc);
    uint16_t* O = z ? Ko : Qo;
    const float osc = (z == 0) ? l2e : 1.0f;
#pragma unroll
    for (int i = 0; i < 4; i++) {
      size_t tok = m0 + wm * 64 + i * 16 + qi;
#pragma unroll
      for (int j = 0; j < 4; j++) {
        int ch = n0 + wn * 64 + j * 16 + g * 4;
        float4 bb = *(const float4*)(bias + ch);
        uint32_t lo = (uint32_t)f2b((acc[i][j][0] + bb.x) * osc) |
                      ((uint32_t)f2b((acc[i][j][1] + bb.y) * osc) << 16);
        uint32_t hi = (uint32_t)f2b((acc[i][j][2] + bb.z) * osc) |
                      ((uint32_t)f2b((acc[i][j][3] + bb.w) * osc) << 16);
        uint2 pk = {lo, hi};
        *(uint2*)(O + tok * D_MODEL + ch) = pk;
      }
    }
  }
}

// -------- output projection: 128x64 tiles, n fastest (X-tile L2 sharing) --------
__global__ __launch_bounds__(256) void oproj_gemm(
    const uint16_t* __restrict__ Ab, const uint16_t* __restrict__ WoT,
    const float* __restrict__ bo, float* __restrict__ out) {
  __shared__ __align__(16) uint16_t As[8192];   // [2][128][32]
  __shared__ __align__(16) uint16_t Bs[4096];   // [2][64][32]
  const int t = threadIdx.x;
  const int lane = t & 63, qi = lane & 15, g = lane >> 4;
  const int wm = (t >> 7) & 1;                  // token-half (64 rows)
  const int wn = (t >> 6) & 1;                  // channel-half (32 cols)
  const int srow = t >> 2;
  const int sc = (t & 3) ^ ((t >> 3) & 3);
  const int wbase = t & 192;
  const int rch = (g ^ ((qi >> 1) & 3)) * 8;
  const int m0 = blockIdx.y * 128, n0 = blockIdx.x * 64;

  const uint16_t* Ag = Ab  + (size_t)(m0 + srow) * D_MODEL + sc * 8;
  const uint16_t* Bg = WoT + (size_t)(n0 + srow) * D_MODEL + sc * 8;

  const f32x4 ZERO = {0.f, 0.f, 0.f, 0.f};
  f32x4 acc[4][2];   // [token-tile][ch-tile], SWAP layout (col=token, rows=channels)
#pragma unroll
  for (int i = 0; i < 4; i++)
#pragma unroll
    for (int j = 0; j < 2; j++) acc[i][j] = ZERO;

  gl2lds16(Ag, As + wbase * 8);
  gl2lds16(Ag + (size_t)64 * D_MODEL, As + (256 + wbase) * 8);
  gl2lds16(Bg, Bs + wbase * 8);

  int cur = 0;
  for (int k0 = 0; k0 < D_MODEL; k0 += 32) {
    __syncthreads();
    int kn = k0 + 32;
    if (kn < D_MODEL) {
      int nbA = (cur ^ 1) * 4096, nbB = (cur ^ 1) * 2048;
      gl2lds16(Ag + kn, As + nbA + wbase * 8);
      gl2lds16(Ag + (size_t)64 * D_MODEL + kn, As + nbA + (256 + wbase) * 8);
      gl2lds16(Bg + kn, Bs + nbB + wbase * 8);
    }
    const uint16_t* Abuf = As + cur * 4096;
    const uint16_t* Bbuf = Bs + cur * 2048;
    bf16x8 af[4], bf[2];
#pragma unroll
    for (int i = 0; i < 4; i++)
      af[i] = *(const bf16x8*)(Abuf + (wm * 64 + i * 16 + qi) * 32 + rch);
#pragma unroll
    for (int j = 0; j < 2; j++)
      bf[j] = *(const bf16x8*)(Bbuf + (wn * 32 + j * 16 + qi) * 32 + rch);
#pragma unroll
    for (int i = 0; i < 4; i++)
#pragma unroll
      for (int j = 0; j < 2; j++)
        acc[i][j] = __builtin_amdgcn_mfma_f32_16x16x32_bf16(bf[j], af[i], acc[i][j], 0, 0, 0);
    cur ^= 1;
  }

#pragma unroll
  for (int i = 0; i < 4; i++) {
    size_t tok = m0 + wm * 64 + i * 16 + qi;
#pragma unroll
    for (int j = 0; j < 2; j++) {
      int ch = n0 + wn * 32 + j * 16 + g * 4;
      float4 bb = *(const float4*)(bo + ch);
      float4 o = {acc[i][j][0] + bb.x, acc[i][j][1] + bb.y,
                  acc[i][j][2] + bb.z, acc[i][j][3] + bb.w};
      *(float4*)(out + tok * D_MODEL + ch) = o;
    }
  }
}

// ------- flash attention: BARRIER-FREE, K/V direct-from-global, LDS only for P -------
// Rounds 1-6 invariant diagnosed: every variant pinned the LDS data path at
// 77-89% of its ~52 TB/s practical b128 ceiling (240KB/CU-iter counting kf+vf+pf
// reads, P+staging writes, + constant 2.1M bank-conflict cycles). Fix: waves read
// K/V MFMA fragments DIRECTLY from global via the same swizzle-cancellation proven
// for Q (canonical chunk g*8) — K/V are L2-resident per XCD (bh-fastest grid) and
// each 16KB tile is L1-shared by the block's 4 waves. Deletes all staging, all
// double-buffering, and ALL barriers (remaining LDS = Ps, wave-private rows).
// LDS traffic -60%; waves free-run and self-stagger so load latency hides behind
// genuinely independent co-resident waves. 4 waves x 32q, grid (32 bh, 16 qt) =
// 512 blocks = 2 blocks/CU, 16KB LDS. vf loads issued before exp2 so their
// latency hides under softmax VALU.
__global__ __launch_bounds__(256, 2) void attn_fwd(
    const uint16_t* __restrict__ Q, const uint16_t* __restrict__ K,
    const uint16_t* __restrict__ Vt, uint16_t* __restrict__ O) {
  __shared__ __align__(16) uint16_t Ps[8192];    // [128 q][64 kk], swizzled, wave-sliced

  const int t = threadIdx.x, lane = t & 63, w = t >> 6;   // w 0..3
  const int g = lane >> 4, qi = lane & 15;
  const int key = qi & 7;                        // Ps swizzle key (= row&7)
  const int q0 = blockIdx.y * 128;
  const int bh = blockIdx.x, b = bh >> 4, h = bh & 15;   // bh fastest -> XCD-local K/V
  const uint16_t* Qp = Q + (size_t)b * SEQ * D_MODEL + h * DKH;
  const uint16_t* Kp = K + (size_t)b * SEQ * D_MODEL + h * DKH;
  const uint16_t* Vp = Vt + (size_t)bh * DKH * SEQ;

  // Q fragments from global (canonical chunk g*8)
  bf16x8 qf[2][2];   // [ks(d-half)][i(q-tile)]
#pragma unroll
  for (int i = 0; i < 2; i++) {
    const uint16_t* Qr = Qp + (size_t)(q0 + w * 32 + i * 16 + qi) * D_MODEL + g * 8;
    qf[0][i] = *(const bf16x8*)(Qr);
    qf[1][i] = *(const bf16x8*)(Qr + 32);
  }

  float lsum[2] = {0.f, 0.f};
  const f32x4 ZERO = {0.f, 0.f, 0.f, 0.f};
  f32x4 oaccT[4][2];   // [d-tile][q-tile]
#pragma unroll
  for (int d = 0; d < 4; d++)
#pragma unroll
    for (int i = 0; i < 2; i++) oaccT[d][i] = ZERO;

  for (int kt = 0; kt < SEQ / 64; kt++) {
    // K fragments direct from global: row = kt*64 + j*16 + qi, cols ks*32 + g*8
    bf16x8 kf[2][4];
#pragma unroll
    for (int j = 0; j < 4; j++) {
      const uint16_t* Kr = Kp + (size_t)(kt * 64 + j * 16 + qi) * D_MODEL + g * 8;
      kf[0][j] = *(const bf16x8*)(Kr);
      kf[1][j] = *(const bf16x8*)(Kr + 32);
    }

    // S^T[kk][q] = K Q^T
    f32x4 sacc[4][2];
#pragma unroll
    for (int j = 0; j < 4; j++)
#pragma unroll
      for (int i = 0; i < 2; i++) sacc[j][i] = ZERO;
#pragma unroll
    for (int ks = 0; ks < 2; ks++) {
      __builtin_amdgcn_s_setprio(1);
#pragma unroll
      for (int j = 0; j < 4; j++)
#pragma unroll
        for (int i = 0; i < 2; i++)
          sacc[j][i] = __builtin_amdgcn_mfma_f32_16x16x32_bf16(kf[ks][j], qf[ks][i], sacc[j][i], 0, 0, 0);
      __builtin_amdgcn_s_setprio(0);
    }

    // V fragments issued now; latency hides under the exp2/pack VALU block.
    // row = channel d*16 + qi, cols = tokens kt*64 + ks*32 + g*8 (Vt layout [bh][ch][tok])
    bf16x8 vf[2][4];
#pragma unroll
    for (int d = 0; d < 4; d++) {
      const uint16_t* Vr = Vp + (size_t)(d * 16 + qi) * SEQ + kt * 64 + g * 8;
      vf[0][d] = *(const bf16x8*)(Vr);
      vf[1][d] = *(const bf16x8*)(Vr + 32);
    }

    // P = exp2(s); pack bf16 (RTZ via v_perm); swizzled b64 stores; l sums fp32 p
#pragma unroll
    for (int i = 0; i < 2; i++) {
      uint16_t* Pr = Ps + (w * 32 + i * 16 + qi) * 64;
#pragma unroll
      for (int j = 0; j < 4; j++) {
        float p0 = __builtin_amdgcn_exp2f(sacc[j][i][0]);
        float p1 = __builtin_amdgcn_exp2f(sacc[j][i][1]);
        float p2 = __builtin_amdgcn_exp2f(sacc[j][i][2]);
        float p3 = __builtin_amdgcn_exp2f(sacc[j][i][3]);
        lsum[i] += (p0 + p1) + (p2 + p3);
        uint2 pk = {__builtin_amdgcn_perm(__builtin_bit_cast(uint32_t, p1),
                                          __builtin_bit_cast(uint32_t, p0), 0x07060302u),
                    __builtin_amdgcn_perm(__builtin_bit_cast(uint32_t, p3),
                                          __builtin_bit_cast(uint32_t, p2), 0x07060302u)};
        *(uint2*)(Pr + (((j * 4 + g) ^ (2 * key)) << 2)) = pk;
      }
    }
    // no barrier anywhere: P round-trip is wave-local (wave w owns rows w*32..+31)

    // O^T[d][q] += V^T P^T
#pragma unroll
    for (int ks = 0; ks < 2; ks++) {
      bf16x8 pf[2];
#pragma unroll
      for (int i = 0; i < 2; i++)
        pf[i] = *(const bf16x8*)(Ps + (w * 32 + i * 16 + qi) * 64 +
                                 (((ks * 4 + g) ^ key) << 3));
      __builtin_amdgcn_s_setprio(1);
#pragma unroll
      for (int d = 0; d < 4; d++)
#pragma unroll
        for (int i = 0; i < 2; i++)
          oaccT[d][i] = __builtin_amdgcn_mfma_f32_16x16x32_bf16(vf[ks][d], pf[i], oaccT[d][i], 0, 0, 0);
      __builtin_amdgcn_s_setprio(0);
    }
  }

  // final l reduction over the 4 lane-groups holding the same q
#pragma unroll
  for (int i = 0; i < 2; i++) {
    lsum[i] += __shfl_xor(lsum[i], 16, 64);
    lsum[i] += __shfl_xor(lsum[i], 32, 64);
  }
  float rl[2] = {1.f / lsum[0], 1.f / lsum[1]};

  // epilogue: O[q][h*64+d] = O^T/l (RNE), 4 consecutive d per 8B store
#pragma unroll
  for (int i = 0; i < 2; i++) {
    size_t row = (size_t)b * SEQ + q0 + w * 32 + i * 16 + qi;
#pragma unroll
    for (int d = 0; d < 4; d++) {
      uint32_t lo = (uint32_t)f2b(oaccT[d][i][0] * rl[i]) |
                    ((uint32_t)f2b(oaccT[d][i][1] * rl[i]) << 16);
      uint32_t hi = (uint32_t)f2b(oaccT[d][i][2] * rl[i]) |
                    ((uint32_t)f2b(oaccT[d][i][3] * rl[i]) << 16);
      uint2 pk = {lo, hi};
      *(uint2*)(O + row * D_MODEL + h * DKH + d * 16 + g * 4) = pk;
    }
  }
}

extern "C" void kernel_launch(void* const* d_in, const int* in_sizes, int n_in,
                              void* d_out, int out_size, void* d_ws, size_t ws_size,
                              hipStream_t stream) {
  (void)in_sizes; (void)n_in; (void)out_size; (void)ws_size;
  const float* X  = (const float*)d_in[0];
  const float* Wq = (const float*)d_in[1];
  const float* bq = (const float*)d_in[2];
  const float* Wk = (const float*)d_in[3];
  const float* bk = (const float*)d_in[4];
  const float* Wv = (const float*)d_in[5];
  const float* bv = (const float*)d_in[6];
  const float* Wo = (const float*)d_in[7];
  const float* bo = (const float*)d_in[8];
  float* out = (float*)d_out;

  char* p = (char*)d_ws;
  uint16_t* Xb  = (uint16_t*)p; p += (size_t)M_TOK * D_MODEL * 2;
  uint16_t* WqT = (uint16_t*)p; p += (size_t)D_MODEL * D_MODEL * 2;
  uint16_t* WkT = (uint16_t*)p; p += (size_t)D_MODEL * D_MODEL * 2;
  uint16_t* WvT = (uint16_t*)p; p += (size_t)D_MODEL * D_MODEL * 2;
  uint16_t* WoT = (uint16_t*)p; p += (size_t)D_MODEL * D_MODEL * 2;
  uint16_t* Qw  = (uint16_t*)p; p += (size_t)M_TOK * D_MODEL * 2;
  uint16_t* Kw  = (uint16_t*)p; p += (size_t)M_TOK * D_MODEL * 2;
  uint16_t* Vt  = (uint16_t*)p; p += (size_t)M_TOK * D_MODEL * 2;
  uint16_t* Ob  = (uint16_t*)p; p += (size_t)M_TOK * D_MODEL * 2;

  prep<<<6144, 256, 0, stream>>>(X, Xb, Wq, Wk, Wv, Wo, WqT, WkT, WvT, WoT);
  qkv_gemm<<<dim3(8, 32, 3), 256, 0, stream>>>(Xb, WqT, WkT, WvT, bq, bk, bv, Qw, Kw, Vt);
  attn_fwd<<<dim3(BATCH * NH, SEQ / 128), 256, 0, stream>>>(Qw, Kw, Vt, Ob);
  oproj_gemm<<<dim3(16, 32), 256, 0, stream>>>(Ob, WoT, bo, out);
}

// Round 8
// 184.432 us; speedup vs baseline: 1.4365x; 1.4365x over previous
//
#include <hip/hip_runtime.h>
#include <stdint.h>

#define D_MODEL 1024
#define NH      16
#define DKH     64
#define BATCH   2
#define SEQ     2048
#define M_TOK   (BATCH*SEQ)   // 4096

typedef __attribute__((ext_vector_type(8))) short bf16x8;   // 8 bf16 = 4 VGPRs
typedef __attribute__((ext_vector_type(4))) float f32x4;    // MFMA C/D

// fp32 -> bf16, round-to-nearest-even
__device__ __forceinline__ uint16_t f2b(float f) {
  uint32_t u = __builtin_bit_cast(uint32_t, f);
  return (uint16_t)((u + 0x7FFFu + ((u >> 16) & 1u)) >> 16);
}

// async global->LDS, 16B per lane. HW writes LDS at wave-uniform base + lane*16.
__device__ __forceinline__ void gl2lds16(const uint16_t* g, uint16_t* l) {
  __builtin_amdgcn_global_load_lds(
      (const __attribute__((address_space(1))) void*)g,
      (__attribute__((address_space(3))) void*)l, 16, 0, 0);
}

// ---- prep: convx (blocks 0..2047) + wtrans x4 (blocks 2048..6143), one launch ----
__global__ __launch_bounds__(256) void prep(
    const float* __restrict__ X, uint16_t* __restrict__ Xb,
    const float* __restrict__ W0, const float* __restrict__ W1,
    const float* __restrict__ W2, const float* __restrict__ W3,
    uint16_t* __restrict__ T0, uint16_t* __restrict__ T1,
    uint16_t* __restrict__ T2, uint16_t* __restrict__ T3) {
  const int bid = blockIdx.x;
  if (bid < 2048) {
    int i = (bid * 256 + threadIdx.x) * 8;
    float4 a = *(const float4*)(X + i);
    float4 b = *(const float4*)(X + i + 4);
    uint16_t tmp[8] = {f2b(a.x), f2b(a.y), f2b(a.z), f2b(a.w),
                       f2b(b.x), f2b(b.y), f2b(b.z), f2b(b.w)};
    *(uint4*)(Xb + i) = *(const uint4*)tmp;
  } else {
    __shared__ float tile[32][33];
    int r = bid - 2048;
    int z = r >> 10, tt = r & 1023;
    const float* W = (z == 0) ? W0 : (z == 1) ? W1 : (z == 2) ? W2 : W3;
    uint16_t*    T = (z == 0) ? T0 : (z == 1) ? T1 : (z == 2) ? T2 : T3;
    int k0 = (tt & 31) * 32, n0 = (tt >> 5) * 32;
    int t = threadIdx.x;
    int rr = t >> 3, c4 = (t & 7) * 4;
    float4 v = *(const float4*)(W + (size_t)(k0 + rr) * D_MODEL + n0 + c4);
    tile[rr][c4] = v.x; tile[rr][c4 + 1] = v.y;
    tile[rr][c4 + 2] = v.z; tile[rr][c4 + 3] = v.w;
    __syncthreads();
    uint16_t o[4] = {f2b(tile[c4][rr]), f2b(tile[c4 + 1][rr]),
                     f2b(tile[c4 + 2][rr]), f2b(tile[c4 + 3][rr])};
    *(uint2*)(T + (size_t)(n0 + rr) * D_MODEL + k0 + c4) = *(const uint2*)o;
  }
}

// ------ 128x128 bf16 MFMA GEMM core: double-buffered LDS, 1 barrier/K-step ------
template <bool SWAP>
__device__ __forceinline__ void gemm_core(const uint16_t* __restrict__ A,
                                          const uint16_t* __restrict__ BT,
                                          uint16_t* As, uint16_t* Bs,
                                          int m0, int n0, int kBeg, int kEnd,
                                          f32x4 (&acc)[4][4]) {
  const int t    = threadIdx.x;
  const int lane = t & 63;
  const int qi   = lane & 15, g = lane >> 4;
  const int wm   = (t >> 7) & 1;
  const int wn   = (t >> 6) & 1;
  const int srow = t >> 2;                       // staging row 0..63
  const int sc   = (t & 3) ^ ((t >> 3) & 3);     // swizzled global chunk
  const int wbase = t & 192;
  const int rch  = (g ^ ((qi >> 1) & 3)) * 8;    // swizzled read chunk (elems)

  const uint16_t* Ag = A  + (size_t)(m0 + srow) * D_MODEL + sc * 8;
  const uint16_t* Bg = BT + (size_t)(n0 + srow) * D_MODEL + sc * 8;

#pragma unroll
  for (int j = 0; j < 2; j++) {
    gl2lds16(Ag + (size_t)j * 64 * D_MODEL + kBeg, As + (j * 256 + wbase) * 8);
    gl2lds16(Bg + (size_t)j * 64 * D_MODEL + kBeg, Bs + (j * 256 + wbase) * 8);
  }

  int cur = 0;
  for (int k0 = kBeg; k0 < kEnd; k0 += 32) {
    __syncthreads();   // publishes buf[cur] (vmcnt drain) + reads of buf[cur^1] done
    int kn = k0 + 32;
    if (kn < kEnd) {
      int nb = (cur ^ 1) * 4096;
#pragma unroll
      for (int j = 0; j < 2; j++) {
        gl2lds16(Ag + (size_t)j * 64 * D_MODEL + kn, As + nb + (j * 256 + wbase) * 8);
        gl2lds16(Bg + (size_t)j * 64 * D_MODEL + kn, Bs + nb + (j * 256 + wbase) * 8);
      }
    }
    const uint16_t* Ab = As + cur * 4096;
    const uint16_t* Bb = Bs + cur * 4096;
    bf16x8 af[4], bf[4];
#pragma unroll
    for (int i = 0; i < 4; i++) {
      af[i] = *(const bf16x8*)(Ab + (wm * 64 + i * 16 + qi) * 32 + rch);
      bf[i] = *(const bf16x8*)(Bb + (wn * 64 + i * 16 + qi) * 32 + rch);
    }
#pragma unroll
    for (int i = 0; i < 4; i++)
#pragma unroll
      for (int j = 0; j < 4; j++)
        acc[i][j] = SWAP
          ? __builtin_amdgcn_mfma_f32_16x16x32_bf16(bf[j], af[i], acc[i][j], 0, 0, 0)
          : __builtin_amdgcn_mfma_f32_16x16x32_bf16(af[i], bf[j], acc[i][j], 0, 0, 0);
    cur ^= 1;
  }
}

// ---------------- fused QKV projection ----------------
// Grid (8 n, 32 m, 3 z): n fastest so consecutive blocks share one X m-tile (L2);
// z slowest so each 2MB weight stays L2-resident per phase.
__global__ __launch_bounds__(256) void qkv_gemm(
    const uint16_t* __restrict__ Xb,
    const uint16_t* __restrict__ WqT, const uint16_t* __restrict__ WkT,
    const uint16_t* __restrict__ WvT,
    const float* __restrict__ bq, const float* __restrict__ bk,
    const float* __restrict__ bv,
    uint16_t* __restrict__ Qo, uint16_t* __restrict__ Ko, uint16_t* __restrict__ Vt) {
  __shared__ __align__(16) uint16_t smem[17408];   // As/Bs dbuf (32KB) aliased with T
  uint16_t* As = smem;                             // [2][128][32]
  uint16_t* Bs = smem + 8192;                      // [2][128][32]
  uint16_t* T  = smem;                             // [128 ch][136] transpose buf (z==2)
  const int z = blockIdx.z;
  const uint16_t* BT  = (z == 0) ? WqT : (z == 1) ? WkT : WvT;
  const float*   bias = (z == 0) ? bq  : (z == 1) ? bk  : bv;
  const int m0 = blockIdx.y * 128, n0 = blockIdx.x * 128;
  const int lane = threadIdx.x & 63, qi = lane & 15, g = lane >> 4;
  const int wm = (threadIdx.x >> 7) & 1, wn = (threadIdx.x >> 6) & 1;
  const float l2e = 1.4426950408889634f * 0.125f;  // log2(e)/sqrt(dk), folded into Q

  const f32x4 ZERO = {0.f, 0.f, 0.f, 0.f};
  f32x4 acc[4][4];
#pragma unroll
  for (int i = 0; i < 4; i++)
#pragma unroll
    for (int j = 0; j < 4; j++) acc[i][j] = ZERO;

  if (z == 2) {
    gemm_core<false>(Xb, BT, As, Bs, m0, n0, 0, D_MODEL, acc);
    __syncthreads();  // all waves done with As/Bs before T overwrite
#pragma unroll
    for (int i = 0; i < 4; i++) {
      int tok = wm * 64 + i * 16 + g * 4;
#pragma unroll
      for (int j = 0; j < 4; j++) {
        int ch = wn * 64 + j * 16 + qi;
        float bb = bias[n0 + ch];
        uint32_t lo = (uint32_t)f2b(acc[i][j][0] + bb) | ((uint32_t)f2b(acc[i][j][1] + bb) << 16);
        uint32_t hi = (uint32_t)f2b(acc[i][j][2] + bb) | ((uint32_t)f2b(acc[i][j][3] + bb) << 16);
        uint2 pk = {lo, hi};
        *(uint2*)(T + ch * 136 + tok) = pk;
      }
    }
    __syncthreads();
    {
      int ch = threadIdx.x >> 1, sh = threadIdx.x & 1;
      const uint16_t* src = T + ch * 136 + sh * 64;
      int bidx = m0 >> 11;
      uint16_t* dst = Vt + ((size_t)(bidx * D_MODEL + n0 + ch)) * SEQ + (m0 & 2047) + sh * 64;
#pragma unroll
      for (int u = 0; u < 8; u++)
        *(uint4*)(dst + u * 8) = *(const uint4*)(src + u * 8);
    }
  } else {
    gemm_core<true>(Xb, BT, As, Bs, m0, n0, 0, D_MODEL, acc);
    uint16_t* O = z ? Ko : Qo;
    const float osc = (z == 0) ? l2e : 1.0f;
#pragma unroll
    for (int i = 0; i < 4; i++) {
      size_t tok = m0 + wm * 64 + i * 16 + qi;
#pragma unroll
      for (int j = 0; j < 4; j++) {
        int ch = n0 + wn * 64 + j * 16 + g * 4;
        float4 bb = *(const float4*)(bias + ch);
        uint32_t lo = (uint32_t)f2b((acc[i][j][0] + bb.x) * osc) |
                      ((uint32_t)f2b((acc[i][j][1] + bb.y) * osc) << 16);
        uint32_t hi = (uint32_t)f2b((acc[i][j][2] + bb.z) * osc) |
                      ((uint32_t)f2b((acc[i][j][3] + bb.w) * osc) << 16);
        uint2 pk = {lo, hi};
        *(uint2*)(O + tok * D_MODEL + ch) = pk;
      }
    }
  }
}

// ---- output projection: full 128x128 gemm_core tile (was 128x64) ----
// 128x64 had half the MFMA-per-ds_read ratio (8 MFMA / 6 b128 vs 16 / 8) and
// half the per-block work -> est. ~300-450 TF. Reuse the proven 128x128 SWAP
// core + qkv's epilogue indexing with fp32 float4 stores. Grid (8 n, 32 m),
// n fastest: the 2MB WoT panel is shared by consecutive blocks in L2.
__global__ __launch_bounds__(256) void oproj_gemm(
    const uint16_t* __restrict__ Ab, const uint16_t* __restrict__ WoT,
    const float* __restrict__ bo, float* __restrict__ out) {
  __shared__ __align__(16) uint16_t smem[16384];   // As/Bs dbuf (32KB)
  uint16_t* As = smem;                             // [2][128][32]
  uint16_t* Bs = smem + 8192;                      // [2][128][32]
  const int lane = threadIdx.x & 63, qi = lane & 15, g = lane >> 4;
  const int wm = (threadIdx.x >> 7) & 1, wn = (threadIdx.x >> 6) & 1;
  const int m0 = blockIdx.y * 128, n0 = blockIdx.x * 128;

  const f32x4 ZERO = {0.f, 0.f, 0.f, 0.f};
  f32x4 acc[4][4];
#pragma unroll
  for (int i = 0; i < 4; i++)
#pragma unroll
    for (int j = 0; j < 4; j++) acc[i][j] = ZERO;

  gemm_core<true>(Ab, WoT, As, Bs, m0, n0, 0, D_MODEL, acc);

#pragma unroll
  for (int i = 0; i < 4; i++) {
    size_t tok = m0 + wm * 64 + i * 16 + qi;
#pragma unroll
    for (int j = 0; j < 4; j++) {
      int ch = n0 + wn * 64 + j * 16 + g * 4;
      float4 bb = *(const float4*)(bo + ch);
      float4 o = {acc[i][j][0] + bb.x, acc[i][j][1] + bb.y,
                  acc[i][j][2] + bb.z, acc[i][j][3] + bb.w};
      *(float4*)(out + tok * D_MODEL + ch) = o;
    }
  }
}

// ------- flash attention: 8 waves (512 thr), 32 q/wave, T15 one-iter-late PV -------
// Restored round-6 version (measured 48.9us; best known). Round-7's K/V-direct-
// from-global regressed 2.5x: per-lane fragment loads have 2048B lane stride ->
// 16 scattered 64B segments per wave instruction on the VMEM path. LDS staging +
// ds_read_b128 is what keeps fragment access dense — keep it.
__global__ __launch_bounds__(512, 2) void attn_fwd(
    const uint16_t* __restrict__ Q, const uint16_t* __restrict__ K,
    const uint16_t* __restrict__ Vt, uint16_t* __restrict__ O) {
  __shared__ __align__(16) uint16_t sm[36864];   // 73728 B
  uint16_t* const Ps = sm + 20480;               // [256 q][64 kk], swizzled

  const int t = threadIdx.x, lane = t & 63, w = t >> 6;   // w 0..7
  const int g = lane >> 4, qi = lane & 15;
  const int rch = (g ^ ((qi >> 1) & 3)) * 8;
  const int key = qi & 7;                        // Ps swizzle key (= row&7)
  const int q0 = blockIdx.y * 256;
  const int bh = blockIdx.x, b = bh >> 4, h = bh & 15;   // bh fastest -> XCD-local K/V
  const uint16_t* Qp = Q + (size_t)b * SEQ * D_MODEL + h * DKH;
  const uint16_t* Kp = K + (size_t)b * SEQ * D_MODEL + h * DKH;
  const uint16_t* Vp = Vt + (size_t)bh * DKH * SEQ;

  // staging decomposition over 512 threads (1 K + 1 V gl2lds per thread per tile)
  const int tt = t & 255, hs = t >> 8;           // hs: which 32-elem half (ks)
  const int srow = tt >> 2;                      // row 0..63
  const int sc = (tt & 3) ^ ((tt >> 3) & 3);     // pre-swizzled global chunk
  const int wbase = tt & 192;                    // wave-uniform LDS base part

  // Q fragments straight from global (swizzle cancels -> canonical chunk g*8)
  bf16x8 qf[2][2];   // [ks(d-half)][i(q-tile)]
#pragma unroll
  for (int i = 0; i < 2; i++) {
    const uint16_t* Qr = Qp + (size_t)(q0 + w * 32 + i * 16 + qi) * D_MODEL + g * 8;
    qf[0][i] = *(const bf16x8*)(Qr);
    qf[1][i] = *(const bf16x8*)(Qr + 32);
  }

  auto STAGE = [&](int tile, uint16_t* kb, uint16_t* vb) {
    gl2lds16(Kp + (size_t)(tile * 64 + srow) * D_MODEL + hs * 32 + sc * 8,
             kb + hs * 2048 + wbase * 8);
    gl2lds16(Vp + (size_t)srow * SEQ + tile * 64 + hs * 32 + sc * 8,
             vb + hs * 2048 + wbase * 8);
  };

  float lsum[2] = {0.f, 0.f};
  const f32x4 ZERO = {0.f, 0.f, 0.f, 0.f};
  f32x4 oaccT[4][2];   // [d-tile][q-tile]
#pragma unroll
  for (int d = 0; d < 4; d++)
#pragma unroll
    for (int i = 0; i < 2; i++) oaccT[d][i] = ZERO;

  // QK(tile) from kb -> sacc; then exp2 -> Ps + lsum
  auto QK_SM = [&](const uint16_t* Kb) {
    f32x4 sacc[4][2];
#pragma unroll
    for (int j = 0; j < 4; j++)
#pragma unroll
      for (int i = 0; i < 2; i++) sacc[j][i] = ZERO;
#pragma unroll
    for (int ks = 0; ks < 2; ks++) {
      const uint16_t* Ksb = Kb + ks * 2048;
      bf16x8 kf[4];
#pragma unroll
      for (int j = 0; j < 4; j++)
        kf[j] = *(const bf16x8*)(Ksb + (j * 16 + qi) * 32 + rch);
      __builtin_amdgcn_s_setprio(1);
#pragma unroll
      for (int j = 0; j < 4; j++)
#pragma unroll
        for (int i = 0; i < 2; i++)
          sacc[j][i] = __builtin_amdgcn_mfma_f32_16x16x32_bf16(kf[j], qf[ks][i], sacc[j][i], 0, 0, 0);
      __builtin_amdgcn_s_setprio(0);
    }
#pragma unroll
    for (int i = 0; i < 2; i++) {
      uint16_t* Pr = Ps + (w * 32 + i * 16 + qi) * 64;
#pragma unroll
      for (int j = 0; j < 4; j++) {
        float p0 = __builtin_amdgcn_exp2f(sacc[j][i][0]);
        float p1 = __builtin_amdgcn_exp2f(sacc[j][i][1]);
        float p2 = __builtin_amdgcn_exp2f(sacc[j][i][2]);
        float p3 = __builtin_amdgcn_exp2f(sacc[j][i][3]);
        lsum[i] += (p0 + p1) + (p2 + p3);
        uint2 pk = {__builtin_amdgcn_perm(__builtin_bit_cast(uint32_t, p1),
                                          __builtin_bit_cast(uint32_t, p0), 0x07060302u),
                    __builtin_amdgcn_perm(__builtin_bit_cast(uint32_t, p3),
                                          __builtin_bit_cast(uint32_t, p2), 0x07060302u)};
        *(uint2*)(Pr + (((j * 4 + g) ^ (2 * key)) << 2)) = pk;
      }
    }
  };

  // PV from vb + current Ps contents -> oaccT
  auto PV = [&](const uint16_t* Vb) {
#pragma unroll
    for (int ks = 0; ks < 2; ks++) {
      const uint16_t* Vsb = Vb + ks * 2048;
      bf16x8 vf[4], pf[2];
#pragma unroll
      for (int d = 0; d < 4; d++)
        vf[d] = *(const bf16x8*)(Vsb + (d * 16 + qi) * 32 + rch);
#pragma unroll
      for (int i = 0; i < 2; i++)
        pf[i] = *(const bf16x8*)(Ps + (w * 32 + i * 16 + qi) * 64 +
                                 (((ks * 4 + g) ^ key) << 3));
      __builtin_amdgcn_s_setprio(1);
#pragma unroll
      for (int d = 0; d < 4; d++)
#pragma unroll
        for (int i = 0; i < 2; i++)
          oaccT[d][i] = __builtin_amdgcn_mfma_f32_16x16x32_bf16(vf[d], pf[i], oaccT[d][i], 0, 0, 0);
      __builtin_amdgcn_s_setprio(0);
    }
  };

  // prologue: stage tiles 0,1; QK(0)+exp2(0)
  STAGE(0, sm, sm + 8192);
  STAGE(1, sm + 4096, sm + 8192 + 4096);
  __syncthreads();            // tiles 0,1 (and Q) visible
  QK_SM(sm);                  // K buf 0
  __syncthreads();            // all waves done reading K0 before iter1 stages tile2->K0

  for (int kt = 1; kt < SEQ / 64; kt++) {
    if (kt + 1 < SEQ / 64)
      STAGE(kt + 1, sm + ((kt + 1) & 1) * 4096,
            sm + 8192 + ((kt + 1) % 3) * 4096);
    const uint16_t* Kb = sm + (kt & 1) * 4096;
    const uint16_t* Vb = sm + 8192 + ((kt - 1) % 3) * 4096;
    // PV(kt-1) first in ds-order (pf reads precede P(kt) writes inside QK_SM);
    // exp2(kt)'s VALU interleaves with PV's MFMAs (independent).
    PV(Vb);
    QK_SM(Kb);
    if (kt + 1 < SEQ / 64) __syncthreads();  // publish tile kt+1; reads of K/V done
  }
  // epilogue PV for the last tile
  PV(sm + 8192 + ((SEQ / 64 - 1) % 3) * 4096);

  // final l reduction over the 4 lane-groups holding the same q
#pragma unroll
  for (int i = 0; i < 2; i++) {
    lsum[i] += __shfl_xor(lsum[i], 16, 64);
    lsum[i] += __shfl_xor(lsum[i], 32, 64);
  }
  float rl[2] = {1.f / lsum[0], 1.f / lsum[1]};

  // epilogue: O[q][h*64+d] = O^T/l (RNE), 4 consecutive d per 8B store
#pragma unroll
  for (int i = 0; i < 2; i++) {
    size_t row = (size_t)b * SEQ + q0 + w * 32 + i * 16 + qi;
#pragma unroll
    for (int d = 0; d < 4; d++) {
      uint32_t lo = (uint32_t)f2b(oaccT[d][i][0] * rl[i]) |
                    ((uint32_t)f2b(oaccT[d][i][1] * rl[i]) << 16);
      uint32_t hi = (uint32_t)f2b(oaccT[d][i][2] * rl[i]) |
                    ((uint32_t)f2b(oaccT[d][i][3] * rl[i]) << 16);
      uint2 pk = {lo, hi};
      *(uint2*)(O + row * D_MODEL + h * DKH + d * 16 + g * 4) = pk;
    }
  }
}

extern "C" void kernel_launch(void* const* d_in, const int* in_sizes, int n_in,
                              void* d_out, int out_size, void* d_ws, size_t ws_size,
                              hipStream_t stream) {
  (void)in_sizes; (void)n_in; (void)out_size; (void)ws_size;
  const float* X  = (const float*)d_in[0];
  const float* Wq = (const float*)d_in[1];
  const float* bq = (const float*)d_in[2];
  const float* Wk = (const float*)d_in[3];
  const float* bk = (const float*)d_in[4];
  const float* Wv = (const float*)d_in[5];
  const float* bv = (const float*)d_in[6];
  const float* Wo = (const float*)d_in[7];
  const float* bo = (const float*)d_in[8];
  float* out = (float*)d_out;

  char* p = (char*)d_ws;
  uint16_t* Xb  = (uint16_t*)p; p += (size_t)M_TOK * D_MODEL * 2;
  uint16_t* WqT = (uint16_t*)p; p += (size_t)D_MODEL * D_MODEL * 2;
  uint16_t* WkT = (uint16_t*)p; p += (size_t)D_MODEL * D_MODEL * 2;
  uint16_t* WvT = (uint16_t*)p; p += (size_t)D_MODEL * D_MODEL * 2;
  uint16_t* WoT = (uint16_t*)p; p += (size_t)D_MODEL * D_MODEL * 2;
  uint16_t* Qw  = (uint16_t*)p; p += (size_t)M_TOK * D_MODEL * 2;
  uint16_t* Kw  = (uint16_t*)p; p += (size_t)M_TOK * D_MODEL * 2;
  uint16_t* Vt  = (uint16_t*)p; p += (size_t)M_TOK * D_MODEL * 2;
  uint16_t* Ob  = (uint16_t*)p; p += (size_t)M_TOK * D_MODEL * 2;

  prep<<<6144, 256, 0, stream>>>(X, Xb, Wq, Wk, Wv, Wo, WqT, WkT, WvT, WoT);
  qkv_gemm<<<dim3(8, 32, 3), 256, 0, stream>>>(Xb, WqT, WkT, WvT, bq, bk, bv, Qw, Kw, Vt);
  attn_fwd<<<dim3(BATCH * NH, SEQ / 256), 512, 0, stream>>>(Qw, Kw, Vt, Ob);
  oproj_gemm<<<dim3(8, 32), 256, 0, stream>>>(Ob, WoT, bo, out);
}

// Round 9
// 183.712 us; speedup vs baseline: 1.4421x; 1.0039x over previous
//
#include <hip/hip_runtime.h>
#include <stdint.h>

#define D_MODEL 1024
#define NH      16
#define DKH     64
#define BATCH   2
#define SEQ     2048
#define M_TOK   (BATCH*SEQ)   // 4096

typedef __attribute__((ext_vector_type(8))) short bf16x8;   // 8 bf16 = 4 VGPRs
typedef __attribute__((ext_vector_type(4))) float f32x4;    // MFMA C/D

// fp32 -> bf16, round-to-nearest-even
__device__ __forceinline__ uint16_t f2b(float f) {
  uint32_t u = __builtin_bit_cast(uint32_t, f);
  return (uint16_t)((u + 0x7FFFu + ((u >> 16) & 1u)) >> 16);
}

// async global->LDS, 16B per lane. HW writes LDS at wave-uniform base + lane*16.
__device__ __forceinline__ void gl2lds16(const uint16_t* g, uint16_t* l) {
  __builtin_amdgcn_global_load_lds(
      (const __attribute__((address_space(1))) void*)g,
      (__attribute__((address_space(3))) void*)l, 16, 0, 0);
}

// ---- prep: convx (blocks 0..2047) + wtrans x4 (blocks 2048..6143), one launch ----
__global__ __launch_bounds__(256) void prep(
    const float* __restrict__ X, uint16_t* __restrict__ Xb,
    const float* __restrict__ W0, const float* __restrict__ W1,
    const float* __restrict__ W2, const float* __restrict__ W3,
    uint16_t* __restrict__ T0, uint16_t* __restrict__ T1,
    uint16_t* __restrict__ T2, uint16_t* __restrict__ T3) {
  const int bid = blockIdx.x;
  if (bid < 2048) {
    int i = (bid * 256 + threadIdx.x) * 8;
    float4 a = *(const float4*)(X + i);
    float4 b = *(const float4*)(X + i + 4);
    uint16_t tmp[8] = {f2b(a.x), f2b(a.y), f2b(a.z), f2b(a.w),
                       f2b(b.x), f2b(b.y), f2b(b.z), f2b(b.w)};
    *(uint4*)(Xb + i) = *(const uint4*)tmp;
  } else {
    __shared__ float tile[32][33];
    int r = bid - 2048;
    int z = r >> 10, tt = r & 1023;
    const float* W = (z == 0) ? W0 : (z == 1) ? W1 : (z == 2) ? W2 : W3;
    uint16_t*    T = (z == 0) ? T0 : (z == 1) ? T1 : (z == 2) ? T2 : T3;
    int k0 = (tt & 31) * 32, n0 = (tt >> 5) * 32;
    int t = threadIdx.x;
    int rr = t >> 3, c4 = (t & 7) * 4;
    float4 v = *(const float4*)(W + (size_t)(k0 + rr) * D_MODEL + n0 + c4);
    tile[rr][c4] = v.x; tile[rr][c4 + 1] = v.y;
    tile[rr][c4 + 2] = v.z; tile[rr][c4 + 3] = v.w;
    __syncthreads();
    uint16_t o[4] = {f2b(tile[c4][rr]), f2b(tile[c4 + 1][rr]),
                     f2b(tile[c4 + 2][rr]), f2b(tile[c4 + 3][rr])};
    *(uint2*)(T + (size_t)(n0 + rr) * D_MODEL + k0 + c4) = *(const uint2*)o;
  }
}

// ------ 128x128 bf16 MFMA GEMM core: double-buffered LDS, 1 barrier/K-step ------
template <bool SWAP>
__device__ __forceinline__ void gemm_core(const uint16_t* __restrict__ A,
                                          const uint16_t* __restrict__ BT,
                                          uint16_t* As, uint16_t* Bs,
                                          int m0, int n0, int kBeg, int kEnd,
                                          f32x4 (&acc)[4][4]) {
  const int t    = threadIdx.x;
  const int lane = t & 63;
  const int qi   = lane & 15, g = lane >> 4;
  const int wm   = (t >> 7) & 1;
  const int wn   = (t >> 6) & 1;
  const int srow = t >> 2;                       // staging row 0..63
  const int sc   = (t & 3) ^ ((t >> 3) & 3);     // swizzled global chunk
  const int wbase = t & 192;
  const int rch  = (g ^ ((qi >> 1) & 3)) * 8;    // swizzled read chunk (elems)

  const uint16_t* Ag = A  + (size_t)(m0 + srow) * D_MODEL + sc * 8;
  const uint16_t* Bg = BT + (size_t)(n0 + srow) * D_MODEL + sc * 8;

#pragma unroll
  for (int j = 0; j < 2; j++) {
    gl2lds16(Ag + (size_t)j * 64 * D_MODEL + kBeg, As + (j * 256 + wbase) * 8);
    gl2lds16(Bg + (size_t)j * 64 * D_MODEL + kBeg, Bs + (j * 256 + wbase) * 8);
  }

  int cur = 0;
  for (int k0 = kBeg; k0 < kEnd; k0 += 32) {
    __syncthreads();   // publishes buf[cur] (vmcnt drain) + reads of buf[cur^1] done
    int kn = k0 + 32;
    if (kn < kEnd) {
      int nb = (cur ^ 1) * 4096;
#pragma unroll
      for (int j = 0; j < 2; j++) {
        gl2lds16(Ag + (size_t)j * 64 * D_MODEL + kn, As + nb + (j * 256 + wbase) * 8);
        gl2lds16(Bg + (size_t)j * 64 * D_MODEL + kn, Bs + nb + (j * 256 + wbase) * 8);
      }
    }
    const uint16_t* Ab = As + cur * 4096;
    const uint16_t* Bb = Bs + cur * 4096;
    bf16x8 af[4], bf[4];
#pragma unroll
    for (int i = 0; i < 4; i++) {
      af[i] = *(const bf16x8*)(Ab + (wm * 64 + i * 16 + qi) * 32 + rch);
      bf[i] = *(const bf16x8*)(Bb + (wn * 64 + i * 16 + qi) * 32 + rch);
    }
#pragma unroll
    for (int i = 0; i < 4; i++)
#pragma unroll
      for (int j = 0; j < 4; j++)
        acc[i][j] = SWAP
          ? __builtin_amdgcn_mfma_f32_16x16x32_bf16(bf[j], af[i], acc[i][j], 0, 0, 0)
          : __builtin_amdgcn_mfma_f32_16x16x32_bf16(af[i], bf[j], acc[i][j], 0, 0, 0);
    cur ^= 1;
  }
}

// ---------------- fused QKV projection ----------------
// 1-D grid 768, XCD-aware decode: x=b&7 (XCD), n=(b>>3)&7, mloc=(b>>6)&3, z=b>>8;
// m = x*4+mloc. Each XCD owns 4 m-tiles -> its Xb working set is 1MB (L2-RESIDENT,
// was 24MB streamed from L3 with n-fastest). The 3 co-resident blocks per CU
// (b, b+256, b+512) share the SAME Xb panel. launch_bounds(256,3) caps VGPR for
// guaranteed 3 blocks/CU.
__global__ __launch_bounds__(256, 3) void qkv_gemm(
    const uint16_t* __restrict__ Xb,
    const uint16_t* __restrict__ WqT, const uint16_t* __restrict__ WkT,
    const uint16_t* __restrict__ WvT,
    const float* __restrict__ bq, const float* __restrict__ bk,
    const float* __restrict__ bv,
    uint16_t* __restrict__ Qo, uint16_t* __restrict__ Ko, uint16_t* __restrict__ Vt) {
  __shared__ __align__(16) uint16_t smem[17408];   // As/Bs dbuf (32KB) aliased with T
  uint16_t* As = smem;                             // [2][128][32]
  uint16_t* Bs = smem + 8192;                      // [2][128][32]
  uint16_t* T  = smem;                             // [128 ch][136] transpose buf (z==2)
  const int bid = blockIdx.x;
  const int xg = bid & 7, nn = (bid >> 3) & 7, mloc = (bid >> 6) & 3;
  const int z = bid >> 8;
  const uint16_t* BT  = (z == 0) ? WqT : (z == 1) ? WkT : WvT;
  const float*   bias = (z == 0) ? bq  : (z == 1) ? bk  : bv;
  const int m0 = (xg * 4 + mloc) * 128, n0 = nn * 128;
  const int lane = threadIdx.x & 63, qi = lane & 15, g = lane >> 4;
  const int wm = (threadIdx.x >> 7) & 1, wn = (threadIdx.x >> 6) & 1;
  const float l2e = 1.4426950408889634f * 0.125f;  // log2(e)/sqrt(dk), folded into Q

  const f32x4 ZERO = {0.f, 0.f, 0.f, 0.f};
  f32x4 acc[4][4];
#pragma unroll
  for (int i = 0; i < 4; i++)
#pragma unroll
    for (int j = 0; j < 4; j++) acc[i][j] = ZERO;

  if (z == 2) {
    gemm_core<false>(Xb, BT, As, Bs, m0, n0, 0, D_MODEL, acc);
    __syncthreads();  // all waves done with As/Bs before T overwrite
#pragma unroll
    for (int i = 0; i < 4; i++) {
      int tok = wm * 64 + i * 16 + g * 4;
#pragma unroll
      for (int j = 0; j < 4; j++) {
        int ch = wn * 64 + j * 16 + qi;
        float bb = bias[n0 + ch];
        uint32_t lo = (uint32_t)f2b(acc[i][j][0] + bb) | ((uint32_t)f2b(acc[i][j][1] + bb) << 16);
        uint32_t hi = (uint32_t)f2b(acc[i][j][2] + bb) | ((uint32_t)f2b(acc[i][j][3] + bb) << 16);
        uint2 pk = {lo, hi};
        *(uint2*)(T + ch * 136 + tok) = pk;
      }
    }
    __syncthreads();
    {
      int ch = threadIdx.x >> 1, sh = threadIdx.x & 1;
      const uint16_t* src = T + ch * 136 + sh * 64;
      int bidx = m0 >> 11;
      uint16_t* dst = Vt + ((size_t)(bidx * D_MODEL + n0 + ch)) * SEQ + (m0 & 2047) + sh * 64;
#pragma unroll
      for (int u = 0; u < 8; u++)
        *(uint4*)(dst + u * 8) = *(const uint4*)(src + u * 8);
    }
  } else {
    gemm_core<true>(Xb, BT, As, Bs, m0, n0, 0, D_MODEL, acc);
    uint16_t* O = z ? Ko : Qo;
    const float osc = (z == 0) ? l2e : 1.0f;
#pragma unroll
    for (int i = 0; i < 4; i++) {
      size_t tok = m0 + wm * 64 + i * 16 + qi;
#pragma unroll
      for (int j = 0; j < 4; j++) {
        int ch = n0 + wn * 64 + j * 16 + g * 4;
        float4 bb = *(const float4*)(bias + ch);
        uint32_t lo = (uint32_t)f2b((acc[i][j][0] + bb.x) * osc) |
                      ((uint32_t)f2b((acc[i][j][1] + bb.y) * osc) << 16);
        uint32_t hi = (uint32_t)f2b((acc[i][j][2] + bb.z) * osc) |
                      ((uint32_t)f2b((acc[i][j][3] + bb.w) * osc) << 16);
        uint2 pk = {lo, hi};
        *(uint2*)(O + tok * D_MODEL + ch) = pk;
      }
    }
  }
}

// ---- output projection: full 128x128 gemm_core tile, n fastest (WoT L2-shared) ----
__global__ __launch_bounds__(256) void oproj_gemm(
    const uint16_t* __restrict__ Ab, const uint16_t* __restrict__ WoT,
    const float* __restrict__ bo, float* __restrict__ out) {
  __shared__ __align__(16) uint16_t smem[16384];   // As/Bs dbuf (32KB)
  uint16_t* As = smem;                             // [2][128][32]
  uint16_t* Bs = smem + 8192;                      // [2][128][32]
  const int lane = threadIdx.x & 63, qi = lane & 15, g = lane >> 4;
  const int wm = (threadIdx.x >> 7) & 1, wn = (threadIdx.x >> 6) & 1;
  const int m0 = blockIdx.y * 128, n0 = blockIdx.x * 128;

  const f32x4 ZERO = {0.f, 0.f, 0.f, 0.f};
  f32x4 acc[4][4];
#pragma unroll
  for (int i = 0; i < 4; i++)
#pragma unroll
    for (int j = 0; j < 4; j++) acc[i][j] = ZERO;

  gemm_core<true>(Ab, WoT, As, Bs, m0, n0, 0, D_MODEL, acc);

#pragma unroll
  for (int i = 0; i < 4; i++) {
    size_t tok = m0 + wm * 64 + i * 16 + qi;
#pragma unroll
    for (int j = 0; j < 4; j++) {
      int ch = n0 + wn * 64 + j * 16 + g * 4;
      float4 bb = *(const float4*)(bo + ch);
      float4 o = {acc[i][j][0] + bb.x, acc[i][j][1] + bb.y,
                  acc[i][j][2] + bb.z, acc[i][j][3] + bb.w};
      *(float4*)(out + tok * D_MODEL + ch) = o;
    }
  }
}

// ------- flash attention: 8 waves, 32 q/wave, counted-vmcnt 4-ring (T4) -------
// Replaces the per-iter __syncthreads (vmcnt(0) drain) with 4-slot K/V rings
// staged 3 tiles ahead + counted "s_waitcnt vmcnt(4)" + raw s_barrier (m201
// idiom). vmcnt(4) at end of iter kt certifies tile kt+1's 2 loads (the only
// VMEM in-loop) are complete before the barrier publishes them. Overwrite
// safety: barrier-per-iter bounds skew to one iter; STAGE targets slot
// (kt+3)&3 = slot(kt-1), whose reads finished before the previous barrier.
// Tail: clamped dummy re-stages of tile 31 keep vmcnt(4) literal-uniform;
// dummy writes land only in already-read slots. LDS 96KB: K ring 32K | V ring
// 32K | Ps 32K. Grid bh-fastest (K/V L2-resident per XCD).
__global__ __launch_bounds__(512, 2) void attn_fwd(
    const uint16_t* __restrict__ Q, const uint16_t* __restrict__ K,
    const uint16_t* __restrict__ Vt, uint16_t* __restrict__ O) {
  __shared__ __align__(16) uint16_t sm[49152];   // 98304 B
  uint16_t* const Ps = sm + 32768;               // [256 q][64 kk], swizzled

  const int t = threadIdx.x, lane = t & 63, w = t >> 6;   // w 0..7
  const int g = lane >> 4, qi = lane & 15;
  const int rch = (g ^ ((qi >> 1) & 3)) * 8;
  const int key = qi & 7;                        // Ps swizzle key (= row&7)
  const int q0 = blockIdx.y * 256;
  const int bh = blockIdx.x, b = bh >> 4, h = bh & 15;   // bh fastest -> XCD-local K/V
  const uint16_t* Qp = Q + (size_t)b * SEQ * D_MODEL + h * DKH;
  const uint16_t* Kp = K + (size_t)b * SEQ * D_MODEL + h * DKH;
  const uint16_t* Vp = Vt + (size_t)bh * DKH * SEQ;

  // staging decomposition over 512 threads (1 K + 1 V gl2lds per thread per tile)
  const int tt = t & 255, hs = t >> 8;           // hs: which 32-elem half (ks)
  const int srow = tt >> 2;                      // row 0..63
  const int sc = (tt & 3) ^ ((tt >> 3) & 3);     // pre-swizzled global chunk
  const int wbase = tt & 192;                    // wave-uniform LDS base part

  // Q fragments straight from global (swizzle cancels -> canonical chunk g*8)
  bf16x8 qf[2][2];   // [ks(d-half)][i(q-tile)]
#pragma unroll
  for (int i = 0; i < 2; i++) {
    const uint16_t* Qr = Qp + (size_t)(q0 + w * 32 + i * 16 + qi) * D_MODEL + g * 8;
    qf[0][i] = *(const bf16x8*)(Qr);
    qf[1][i] = *(const bf16x8*)(Qr + 32);
  }

  auto STAGE = [&](int tile, int slot) {
    gl2lds16(Kp + (size_t)(tile * 64 + srow) * D_MODEL + hs * 32 + sc * 8,
             sm + slot * 4096 + hs * 2048 + wbase * 8);
    gl2lds16(Vp + (size_t)srow * SEQ + tile * 64 + hs * 32 + sc * 8,
             sm + 16384 + slot * 4096 + hs * 2048 + wbase * 8);
  };

  float lsum[2] = {0.f, 0.f};
  const f32x4 ZERO = {0.f, 0.f, 0.f, 0.f};
  f32x4 oaccT[4][2];   // [d-tile][q-tile]
#pragma unroll
  for (int d = 0; d < 4; d++)
#pragma unroll
    for (int i = 0; i < 2; i++) oaccT[d][i] = ZERO;

  // QK(tile) from Kb -> sacc; exp2 -> Ps + lsum
  auto QK_SM = [&](const uint16_t* Kb) {
    f32x4 sacc[4][2];
#pragma unroll
    for (int j = 0; j < 4; j++)
#pragma unroll
      for (int i = 0; i < 2; i++) sacc[j][i] = ZERO;
#pragma unroll
    for (int ks = 0; ks < 2; ks++) {
      const uint16_t* Ksb = Kb + ks * 2048;
      bf16x8 kf[4];
#pragma unroll
      for (int j = 0; j < 4; j++)
        kf[j] = *(const bf16x8*)(Ksb + (j * 16 + qi) * 32 + rch);
      __builtin_amdgcn_s_setprio(1);
#pragma unroll
      for (int j = 0; j < 4; j++)
#pragma unroll
        for (int i = 0; i < 2; i++)
          sacc[j][i] = __builtin_amdgcn_mfma_f32_16x16x32_bf16(kf[j], qf[ks][i], sacc[j][i], 0, 0, 0);
      __builtin_amdgcn_s_setprio(0);
    }
#pragma unroll
    for (int i = 0; i < 2; i++) {
      uint16_t* Pr = Ps + (w * 32 + i * 16 + qi) * 64;
#pragma unroll
      for (int j = 0; j < 4; j++) {
        float p0 = __builtin_amdgcn_exp2f(sacc[j][i][0]);
        float p1 = __builtin_amdgcn_exp2f(sacc[j][i][1]);
        float p2 = __builtin_amdgcn_exp2f(sacc[j][i][2]);
        float p3 = __builtin_amdgcn_exp2f(sacc[j][i][3]);
        lsum[i] += (p0 + p1) + (p2 + p3);
        uint2 pk = {__builtin_amdgcn_perm(__builtin_bit_cast(uint32_t, p1),
                                          __builtin_bit_cast(uint32_t, p0), 0x07060302u),
                    __builtin_amdgcn_perm(__builtin_bit_cast(uint32_t, p3),
                                          __builtin_bit_cast(uint32_t, p2), 0x07060302u)};
        *(uint2*)(Pr + (((j * 4 + g) ^ (2 * key)) << 2)) = pk;
      }
    }
  };

  // PV from Vb + current Ps contents -> oaccT
  auto PV = [&](const uint16_t* Vb) {
#pragma unroll
    for (int ks = 0; ks < 2; ks++) {
      const uint16_t* Vsb = Vb + ks * 2048;
      bf16x8 vf[4], pf[2];
#pragma unroll
      for (int d = 0; d < 4; d++)
        vf[d] = *(const bf16x8*)(Vsb + (d * 16 + qi) * 32 + rch);
#pragma unroll
      for (int i = 0; i < 2; i++)
        pf[i] = *(const bf16x8*)(Ps + (w * 32 + i * 16 + qi) * 64 +
                                 (((ks * 4 + g) ^ key) << 3));
      __builtin_amdgcn_s_setprio(1);
#pragma unroll
      for (int d = 0; d < 4; d++)
#pragma unroll
        for (int i = 0; i < 2; i++)
          oaccT[d][i] = __builtin_amdgcn_mfma_f32_16x16x32_bf16(vf[d], pf[i], oaccT[d][i], 0, 0, 0);
      __builtin_amdgcn_s_setprio(0);
    }
  };

  // prologue: stage tiles 0,1,2 into slots 0,1,2; certify tile 0; publish
  STAGE(0, 0); STAGE(1, 1); STAGE(2, 2);
  asm volatile("s_waitcnt vmcnt(4)" ::: "memory");   // tile 0's 2 loads done
  __builtin_amdgcn_s_barrier();
  asm volatile("" ::: "memory");

  for (int kt = 0; kt < SEQ / 64; kt++) {
    int st = kt + 3;
    if (st > SEQ / 64 - 1) st = SEQ / 64 - 1;        // clamped dummy re-stage (tail)
    STAGE(st, (kt + 3) & 3);
    const uint16_t* Kb = sm + (kt & 3) * 4096;
    const uint16_t* Vb = sm + 16384 + (kt & 3) * 4096;
    QK_SM(Kb);
    PV(Vb);
    asm volatile("s_waitcnt vmcnt(4)" ::: "memory"); // tile kt+1 loads complete
    __builtin_amdgcn_s_barrier();                    // publish to all waves
    asm volatile("" ::: "memory");
  }

  // final l reduction over the 4 lane-groups holding the same q
#pragma unroll
  for (int i = 0; i < 2; i++) {
    lsum[i] += __shfl_xor(lsum[i], 16, 64);
    lsum[i] += __shfl_xor(lsum[i], 32, 64);
  }
  float rl[2] = {1.f / lsum[0], 1.f / lsum[1]};

  // epilogue: O[q][h*64+d] = O^T/l (RNE), 4 consecutive d per 8B store
#pragma unroll
  for (int i = 0; i < 2; i++) {
    size_t row = (size_t)b * SEQ + q0 + w * 32 + i * 16 + qi;
#pragma unroll
    for (int d = 0; d < 4; d++) {
      uint32_t lo = (uint32_t)f2b(oaccT[d][i][0] * rl[i]) |
                    ((uint32_t)f2b(oaccT[d][i][1] * rl[i]) << 16);
      uint32_t hi = (uint32_t)f2b(oaccT[d][i][2] * rl[i]) |
                    ((uint32_t)f2b(oaccT[d][i][3] * rl[i]) << 16);
      uint2 pk = {lo, hi};
      *(uint2*)(O + row * D_MODEL + h * DKH + d * 16 + g * 4) = pk;
    }
  }
}

extern "C" void kernel_launch(void* const* d_in, const int* in_sizes, int n_in,
                              void* d_out, int out_size, void* d_ws, size_t ws_size,
                              hipStream_t stream) {
  (void)in_sizes; (void)n_in; (void)out_size; (void)ws_size;
  const float* X  = (const float*)d_in[0];
  const float* Wq = (const float*)d_in[1];
  const float* bq = (const float*)d_in[2];
  const float* Wk = (const float*)d_in[3];
  const float* bk = (const float*)d_in[4];
  const float* Wv = (const float*)d_in[5];
  const float* bv = (const float*)d_in[6];
  const float* Wo = (const float*)d_in[7];
  const float* bo = (const float*)d_in[8];
  float* out = (float*)d_out;

  char* p = (char*)d_ws;
  uint16_t* Xb  = (uint16_t*)p; p += (size_t)M_TOK * D_MODEL * 2;
  uint16_t* WqT = (uint16_t*)p; p += (size_t)D_MODEL * D_MODEL * 2;
  uint16_t* WkT = (uint16_t*)p; p += (size_t)D_MODEL * D_MODEL * 2;
  uint16_t* WvT = (uint16_t*)p; p += (size_t)D_MODEL * D_MODEL * 2;
  uint16_t* WoT = (uint16_t*)p; p += (size_t)D_MODEL * D_MODEL * 2;
  uint16_t* Qw  = (uint16_t*)p; p += (size_t)M_TOK * D_MODEL * 2;
  uint16_t* Kw  = (uint16_t*)p; p += (size_t)M_TOK * D_MODEL * 2;
  uint16_t* Vt  = (uint16_t*)p; p += (size_t)M_TOK * D_MODEL * 2;
  uint16_t* Ob  = (uint16_t*)p; p += (size_t)M_TOK * D_MODEL * 2;

  prep<<<6144, 256, 0, stream>>>(X, Xb, Wq, Wk, Wv, Wo, WqT, WkT, WvT, WoT);
  qkv_gemm<<<768, 256, 0, stream>>>(Xb, WqT, WkT, WvT, bq, bk, bv, Qw, Kw, Vt);
  attn_fwd<<<dim3(BATCH * NH, SEQ / 256), 512, 0, stream>>>(Qw, Kw, Vt, Ob);
  oproj_gemm<<<dim3(8, 32), 256, 0, stream>>>(Ob, WoT, bo, out);
}

// Round 10
// 181.381 us; speedup vs baseline: 1.4607x; 1.0129x over previous
//
#include <hip/hip_runtime.h>
#include <stdint.h>

#define D_MODEL 1024
#define NH      16
#define DKH     64
#define BATCH   2
#define SEQ     2048
#define M_TOK   (BATCH*SEQ)   // 4096

typedef __attribute__((ext_vector_type(8))) short bf16x8;   // 8 bf16 = 4 VGPRs
typedef __attribute__((ext_vector_type(4))) float f32x4;    // MFMA C/D

// fp32 -> bf16, round-to-nearest-even
__device__ __forceinline__ uint16_t f2b(float f) {
  uint32_t u = __builtin_bit_cast(uint32_t, f);
  return (uint16_t)((u + 0x7FFFu + ((u >> 16) & 1u)) >> 16);
}

// async global->LDS, 16B per lane. HW writes LDS at wave-uniform base + lane*16.
__device__ __forceinline__ void gl2lds16(const uint16_t* g, uint16_t* l) {
  __builtin_amdgcn_global_load_lds(
      (const __attribute__((address_space(1))) void*)g,
      (__attribute__((address_space(3))) void*)l, 16, 0, 0);
}

// ---- prep: convx (blocks 0..2047) + wtrans x4 (blocks 2048..6143), one launch ----
__global__ __launch_bounds__(256) void prep(
    const float* __restrict__ X, uint16_t* __restrict__ Xb,
    const float* __restrict__ W0, const float* __restrict__ W1,
    const float* __restrict__ W2, const float* __restrict__ W3,
    uint16_t* __restrict__ T0, uint16_t* __restrict__ T1,
    uint16_t* __restrict__ T2, uint16_t* __restrict__ T3) {
  const int bid = blockIdx.x;
  if (bid < 2048) {
    int i = (bid * 256 + threadIdx.x) * 8;
    float4 a = *(const float4*)(X + i);
    float4 b = *(const float4*)(X + i + 4);
    uint16_t tmp[8] = {f2b(a.x), f2b(a.y), f2b(a.z), f2b(a.w),
                       f2b(b.x), f2b(b.y), f2b(b.z), f2b(b.w)};
    *(uint4*)(Xb + i) = *(const uint4*)tmp;
  } else {
    __shared__ float tile[32][33];
    int r = bid - 2048;
    int z = r >> 10, tt = r & 1023;
    const float* W = (z == 0) ? W0 : (z == 1) ? W1 : (z == 2) ? W2 : W3;
    uint16_t*    T = (z == 0) ? T0 : (z == 1) ? T1 : (z == 2) ? T2 : T3;
    int k0 = (tt & 31) * 32, n0 = (tt >> 5) * 32;
    int t = threadIdx.x;
    int rr = t >> 3, c4 = (t & 7) * 4;
    float4 v = *(const float4*)(W + (size_t)(k0 + rr) * D_MODEL + n0 + c4);
    tile[rr][c4] = v.x; tile[rr][c4 + 1] = v.y;
    tile[rr][c4 + 2] = v.z; tile[rr][c4 + 3] = v.w;
    __syncthreads();
    uint16_t o[4] = {f2b(tile[c4][rr]), f2b(tile[c4 + 1][rr]),
                     f2b(tile[c4 + 2][rr]), f2b(tile[c4 + 3][rr])};
    *(uint2*)(T + (size_t)(n0 + rr) * D_MODEL + k0 + c4) = *(const uint2*)o;
  }
}

// ------ 128x128 bf16 MFMA GEMM core: double-buffered LDS, 1 barrier/K-step ------
template <bool SWAP>
__device__ __forceinline__ void gemm_core(const uint16_t* __restrict__ A,
                                          const uint16_t* __restrict__ BT,
                                          uint16_t* As, uint16_t* Bs,
                                          int m0, int n0, int kBeg, int kEnd,
                                          f32x4 (&acc)[4][4]) {
  const int t    = threadIdx.x;
  const int lane = t & 63;
  const int qi   = lane & 15, g = lane >> 4;
  const int wm   = (t >> 7) & 1;
  const int wn   = (t >> 6) & 1;
  const int srow = t >> 2;                       // staging row 0..63
  const int sc   = (t & 3) ^ ((t >> 3) & 3);     // swizzled global chunk
  const int wbase = t & 192;
  const int rch  = (g ^ ((qi >> 1) & 3)) * 8;    // swizzled read chunk (elems)

  const uint16_t* Ag = A  + (size_t)(m0 + srow) * D_MODEL + sc * 8;
  const uint16_t* Bg = BT + (size_t)(n0 + srow) * D_MODEL + sc * 8;

#pragma unroll
  for (int j = 0; j < 2; j++) {
    gl2lds16(Ag + (size_t)j * 64 * D_MODEL + kBeg, As + (j * 256 + wbase) * 8);
    gl2lds16(Bg + (size_t)j * 64 * D_MODEL + kBeg, Bs + (j * 256 + wbase) * 8);
  }

  int cur = 0;
  for (int k0 = kBeg; k0 < kEnd; k0 += 32) {
    __syncthreads();   // publishes buf[cur] (vmcnt drain) + reads of buf[cur^1] done
    int kn = k0 + 32;
    if (kn < kEnd) {
      int nb = (cur ^ 1) * 4096;
#pragma unroll
      for (int j = 0; j < 2; j++) {
        gl2lds16(Ag + (size_t)j * 64 * D_MODEL + kn, As + nb + (j * 256 + wbase) * 8);
        gl2lds16(Bg + (size_t)j * 64 * D_MODEL + kn, Bs + nb + (j * 256 + wbase) * 8);
      }
    }
    const uint16_t* Ab = As + cur * 4096;
    const uint16_t* Bb = Bs + cur * 4096;
    bf16x8 af[4], bf[4];
#pragma unroll
    for (int i = 0; i < 4; i++) {
      af[i] = *(const bf16x8*)(Ab + (wm * 64 + i * 16 + qi) * 32 + rch);
      bf[i] = *(const bf16x8*)(Bb + (wn * 64 + i * 16 + qi) * 32 + rch);
    }
#pragma unroll
    for (int i = 0; i < 4; i++)
#pragma unroll
      for (int j = 0; j < 4; j++)
        acc[i][j] = SWAP
          ? __builtin_amdgcn_mfma_f32_16x16x32_bf16(bf[j], af[i], acc[i][j], 0, 0, 0)
          : __builtin_amdgcn_mfma_f32_16x16x32_bf16(af[i], bf[j], acc[i][j], 0, 0, 0);
    cur ^= 1;
  }
}

// ---------------- fused QKV projection ----------------
// 1-D grid 768, XCD-aware decode: x=b&7 (XCD), n=(b>>3)&7, mloc=(b>>6)&3, z=b>>8;
// m = x*4+mloc. Xb working set 1MB/XCD (L2-resident). 3 blocks/CU (covered-drain
// regime -> counted-vmcnt would be null per m131/m139; left as-is).
__global__ __launch_bounds__(256, 3) void qkv_gemm(
    const uint16_t* __restrict__ Xb,
    const uint16_t* __restrict__ WqT, const uint16_t* __restrict__ WkT,
    const uint16_t* __restrict__ WvT,
    const float* __restrict__ bq, const float* __restrict__ bk,
    const float* __restrict__ bv,
    uint16_t* __restrict__ Qo, uint16_t* __restrict__ Ko, uint16_t* __restrict__ Vt) {
  __shared__ __align__(16) uint16_t smem[17408];   // As/Bs dbuf (32KB) aliased with T
  uint16_t* As = smem;                             // [2][128][32]
  uint16_t* Bs = smem + 8192;                      // [2][128][32]
  uint16_t* T  = smem;                             // [128 ch][136] transpose buf (z==2)
  const int bid = blockIdx.x;
  const int xg = bid & 7, nn = (bid >> 3) & 7, mloc = (bid >> 6) & 3;
  const int z = bid >> 8;
  const uint16_t* BT  = (z == 0) ? WqT : (z == 1) ? WkT : WvT;
  const float*   bias = (z == 0) ? bq  : (z == 1) ? bk  : bv;
  const int m0 = (xg * 4 + mloc) * 128, n0 = nn * 128;
  const int lane = threadIdx.x & 63, qi = lane & 15, g = lane >> 4;
  const int wm = (threadIdx.x >> 7) & 1, wn = (threadIdx.x >> 6) & 1;
  const float l2e = 1.4426950408889634f * 0.125f;  // log2(e)/sqrt(dk), folded into Q

  const f32x4 ZERO = {0.f, 0.f, 0.f, 0.f};
  f32x4 acc[4][4];
#pragma unroll
  for (int i = 0; i < 4; i++)
#pragma unroll
    for (int j = 0; j < 4; j++) acc[i][j] = ZERO;

  if (z == 2) {
    gemm_core<false>(Xb, BT, As, Bs, m0, n0, 0, D_MODEL, acc);
    __syncthreads();  // all waves done with As/Bs before T overwrite
#pragma unroll
    for (int i = 0; i < 4; i++) {
      int tok = wm * 64 + i * 16 + g * 4;
#pragma unroll
      for (int j = 0; j < 4; j++) {
        int ch = wn * 64 + j * 16 + qi;
        float bb = bias[n0 + ch];
        uint32_t lo = (uint32_t)f2b(acc[i][j][0] + bb) | ((uint32_t)f2b(acc[i][j][1] + bb) << 16);
        uint32_t hi = (uint32_t)f2b(acc[i][j][2] + bb) | ((uint32_t)f2b(acc[i][j][3] + bb) << 16);
        uint2 pk = {lo, hi};
        *(uint2*)(T + ch * 136 + tok) = pk;
      }
    }
    __syncthreads();
    {
      int ch = threadIdx.x >> 1, sh = threadIdx.x & 1;
      const uint16_t* src = T + ch * 136 + sh * 64;
      int bidx = m0 >> 11;
      uint16_t* dst = Vt + ((size_t)(bidx * D_MODEL + n0 + ch)) * SEQ + (m0 & 2047) + sh * 64;
#pragma unroll
      for (int u = 0; u < 8; u++)
        *(uint4*)(dst + u * 8) = *(const uint4*)(src + u * 8);
    }
  } else {
    gemm_core<true>(Xb, BT, As, Bs, m0, n0, 0, D_MODEL, acc);
    uint16_t* O = z ? Ko : Qo;
    const float osc = (z == 0) ? l2e : 1.0f;
#pragma unroll
    for (int i = 0; i < 4; i++) {
      size_t tok = m0 + wm * 64 + i * 16 + qi;
#pragma unroll
      for (int j = 0; j < 4; j++) {
        int ch = n0 + wn * 64 + j * 16 + g * 4;
        float4 bb = *(const float4*)(bias + ch);
        uint32_t lo = (uint32_t)f2b((acc[i][j][0] + bb.x) * osc) |
                      ((uint32_t)f2b((acc[i][j][1] + bb.y) * osc) << 16);
        uint32_t hi = (uint32_t)f2b((acc[i][j][2] + bb.z) * osc) |
                      ((uint32_t)f2b((acc[i][j][3] + bb.w) * osc) << 16);
        uint2 pk = {lo, hi};
        *(uint2*)(O + tok * D_MODEL + ch) = pk;
      }
    }
  }
}

// ---- output projection: 128x128 tile, counted-vmcnt 4-slot ring (drain-exposed fix) ----
// Grid 256 blocks = exactly 1 block/CU: no co-resident waves cover the per-K-step
// vmcnt(0) drain of __syncthreads (m139's null was measured in the covered regime;
// here the drain is exposed ~32 x ~500cy). Ring: 4 slots x (A 8KB + B 8KB), staged
// 3 steps ahead; s_waitcnt vmcnt(8) (12 in flight steady; 8 newest outstanding
// certifies step kt+1's 4 loads) + raw s_barrier. Tail: clamped dummy re-stages of
// step 31 land only in slots whose readers already passed a barrier.
__global__ __launch_bounds__(256) void oproj_gemm(
    const uint16_t* __restrict__ Ab, const uint16_t* __restrict__ WoT,
    const float* __restrict__ bo, float* __restrict__ out) {
  __shared__ __align__(16) uint16_t sm[32768];   // 64KB: A ring [0,16384), B ring [16384,32768)
  const int t = threadIdx.x;
  const int lane = t & 63, qi = lane & 15, g = lane >> 4;
  const int wm = (t >> 7) & 1, wn = (t >> 6) & 1;
  const int srow = t >> 2;
  const int sc = (t & 3) ^ ((t >> 3) & 3);
  const int wbase = t & 192;
  const int rch = (g ^ ((qi >> 1) & 3)) * 8;
  const int m0 = blockIdx.y * 128, n0 = blockIdx.x * 128;

  const uint16_t* Ag = Ab  + (size_t)(m0 + srow) * D_MODEL + sc * 8;
  const uint16_t* Bg = WoT + (size_t)(n0 + srow) * D_MODEL + sc * 8;

  auto STAGE = [&](int k0, int slot) {
    uint16_t* As = sm + slot * 4096;             // 8KB slot
    uint16_t* Bs = sm + 16384 + slot * 4096;
    gl2lds16(Ag + k0,                     As + wbase * 8);
    gl2lds16(Ag + (size_t)64 * D_MODEL + k0, As + (256 + wbase) * 8);
    gl2lds16(Bg + k0,                     Bs + wbase * 8);
    gl2lds16(Bg + (size_t)64 * D_MODEL + k0, Bs + (256 + wbase) * 8);
  };

  const f32x4 ZERO = {0.f, 0.f, 0.f, 0.f};
  f32x4 acc[4][4];
#pragma unroll
  for (int i = 0; i < 4; i++)
#pragma unroll
    for (int j = 0; j < 4; j++) acc[i][j] = ZERO;

  STAGE(0, 0); STAGE(32, 1); STAGE(64, 2);
  asm volatile("s_waitcnt vmcnt(8)" ::: "memory");   // step 0's 4 loads done
  __builtin_amdgcn_s_barrier();
  asm volatile("" ::: "memory");

  for (int kt = 0; kt < 32; kt++) {
    int ks = kt + 3; if (ks > 31) ks = 31;           // clamped dummy tail stage
    STAGE(ks * 32, (kt + 3) & 3);
    const uint16_t* Abuf = sm + (kt & 3) * 4096;
    const uint16_t* Bbuf = sm + 16384 + (kt & 3) * 4096;
    bf16x8 af[4], bf[4];
#pragma unroll
    for (int i = 0; i < 4; i++) {
      af[i] = *(const bf16x8*)(Abuf + (wm * 64 + i * 16 + qi) * 32 + rch);
      bf[i] = *(const bf16x8*)(Bbuf + (wn * 64 + i * 16 + qi) * 32 + rch);
    }
#pragma unroll
    for (int i = 0; i < 4; i++)
#pragma unroll
      for (int j = 0; j < 4; j++)
        acc[i][j] = __builtin_amdgcn_mfma_f32_16x16x32_bf16(bf[j], af[i], acc[i][j], 0, 0, 0);
    asm volatile("s_waitcnt vmcnt(8)" ::: "memory"); // step kt+1 loads complete
    __builtin_amdgcn_s_barrier();                    // publish to all waves
    asm volatile("" ::: "memory");
  }

#pragma unroll
  for (int i = 0; i < 4; i++) {
    size_t tok = m0 + wm * 64 + i * 16 + qi;
#pragma unroll
    for (int j = 0; j < 4; j++) {
      int ch = n0 + wn * 64 + j * 16 + g * 4;
      float4 bb = *(const float4*)(bo + ch);
      float4 o = {acc[i][j][0] + bb.x, acc[i][j][1] + bb.y,
                  acc[i][j][2] + bb.z, acc[i][j][3] + bb.w};
      *(float4*)(out + tok * D_MODEL + ch) = o;
    }
  }
}

// ------- flash attention: 8 waves, 32 q/wave, counted-vmcnt 4-ring (frozen) -------
// 49.0us across 6 structural variants -> structural floor for this fragment scheme
// (700 TF = 78% of the m214 ladder's ~900). 32 q/wave is forced: 65536 (q,head)
// rows total; 64 q/wave would leave 1 wave/SIMD.
__global__ __launch_bounds__(512, 2) void attn_fwd(
    const uint16_t* __restrict__ Q, const uint16_t* __restrict__ K,
    const uint16_t* __restrict__ Vt, uint16_t* __restrict__ O) {
  __shared__ __align__(16) uint16_t sm[49152];   // 98304 B
  uint16_t* const Ps = sm + 32768;               // [256 q][64 kk], swizzled

  const int t = threadIdx.x, lane = t & 63, w = t >> 6;   // w 0..7
  const int g = lane >> 4, qi = lane & 15;
  const int rch = (g ^ ((qi >> 1) & 3)) * 8;
  const int key = qi & 7;                        // Ps swizzle key (= row&7)
  const int q0 = blockIdx.y * 256;
  const int bh = blockIdx.x, b = bh >> 4, h = bh & 15;   // bh fastest -> XCD-local K/V
  const uint16_t* Qp = Q + (size_t)b * SEQ * D_MODEL + h * DKH;
  const uint16_t* Kp = K + (size_t)b * SEQ * D_MODEL + h * DKH;
  const uint16_t* Vp = Vt + (size_t)bh * DKH * SEQ;

  // staging decomposition over 512 threads (1 K + 1 V gl2lds per thread per tile)
  const int tt = t & 255, hs = t >> 8;           // hs: which 32-elem half (ks)
  const int srow = tt >> 2;                      // row 0..63
  const int sc = (tt & 3) ^ ((tt >> 3) & 3);     // pre-swizzled global chunk
  const int wbase = tt & 192;                    // wave-uniform LDS base part

  // Q fragments straight from global (swizzle cancels -> canonical chunk g*8)
  bf16x8 qf[2][2];   // [ks(d-half)][i(q-tile)]
#pragma unroll
  for (int i = 0; i < 2; i++) {
    const uint16_t* Qr = Qp + (size_t)(q0 + w * 32 + i * 16 + qi) * D_MODEL + g * 8;
    qf[0][i] = *(const bf16x8*)(Qr);
    qf[1][i] = *(const bf16x8*)(Qr + 32);
  }

  auto STAGE = [&](int tile, int slot) {
    gl2lds16(Kp + (size_t)(tile * 64 + srow) * D_MODEL + hs * 32 + sc * 8,
             sm + slot * 4096 + hs * 2048 + wbase * 8);
    gl2lds16(Vp + (size_t)srow * SEQ + tile * 64 + hs * 32 + sc * 8,
             sm + 16384 + slot * 4096 + hs * 2048 + wbase * 8);
  };

  float lsum[2] = {0.f, 0.f};
  const f32x4 ZERO = {0.f, 0.f, 0.f, 0.f};
  f32x4 oaccT[4][2];   // [d-tile][q-tile]
#pragma unroll
  for (int d = 0; d < 4; d++)
#pragma unroll
    for (int i = 0; i < 2; i++) oaccT[d][i] = ZERO;

  // QK(tile) from Kb -> sacc; exp2 -> Ps + lsum
  auto QK_SM = [&](const uint16_t* Kb) {
    f32x4 sacc[4][2];
#pragma unroll
    for (int j = 0; j < 4; j++)
#pragma unroll
      for (int i = 0; i < 2; i++) sacc[j][i] = ZERO;
#pragma unroll
    for (int ks = 0; ks < 2; ks++) {
      const uint16_t* Ksb = Kb + ks * 2048;
      bf16x8 kf[4];
#pragma unroll
      for (int j = 0; j < 4; j++)
        kf[j] = *(const bf16x8*)(Ksb + (j * 16 + qi) * 32 + rch);
      __builtin_amdgcn_s_setprio(1);
#pragma unroll
      for (int j = 0; j < 4; j++)
#pragma unroll
        for (int i = 0; i < 2; i++)
          sacc[j][i] = __builtin_amdgcn_mfma_f32_16x16x32_bf16(kf[j], qf[ks][i], sacc[j][i], 0, 0, 0);
      __builtin_amdgcn_s_setprio(0);
    }
#pragma unroll
    for (int i = 0; i < 2; i++) {
      uint16_t* Pr = Ps + (w * 32 + i * 16 + qi) * 64;
#pragma unroll
      for (int j = 0; j < 4; j++) {
        float p0 = __builtin_amdgcn_exp2f(sacc[j][i][0]);
        float p1 = __builtin_amdgcn_exp2f(sacc[j][i][1]);
        float p2 = __builtin_amdgcn_exp2f(sacc[j][i][2]);
        float p3 = __builtin_amdgcn_exp2f(sacc[j][i][3]);
        lsum[i] += (p0 + p1) + (p2 + p3);
        uint2 pk = {__builtin_amdgcn_perm(__builtin_bit_cast(uint32_t, p1),
                                          __builtin_bit_cast(uint32_t, p0), 0x07060302u),
                    __builtin_amdgcn_perm(__builtin_bit_cast(uint32_t, p3),
                                          __builtin_bit_cast(uint32_t, p2), 0x07060302u)};
        *(uint2*)(Pr + (((j * 4 + g) ^ (2 * key)) << 2)) = pk;
      }
    }
  };

  // PV from Vb + current Ps contents -> oaccT
  auto PV = [&](const uint16_t* Vb) {
#pragma unroll
    for (int ks = 0; ks < 2; ks++) {
      const uint16_t* Vsb = Vb + ks * 2048;
      bf16x8 vf[4], pf[2];
#pragma unroll
      for (int d = 0; d < 4; d++)
        vf[d] = *(const bf16x8*)(Vsb + (d * 16 + qi) * 32 + rch);
#pragma unroll
      for (int i = 0; i < 2; i++)
        pf[i] = *(const bf16x8*)(Ps + (w * 32 + i * 16 + qi) * 64 +
                                 (((ks * 4 + g) ^ key) << 3));
      __builtin_amdgcn_s_setprio(1);
#pragma unroll
      for (int d = 0; d < 4; d++)
#pragma unroll
        for (int i = 0; i < 2; i++)
          oaccT[d][i] = __builtin_amdgcn_mfma_f32_16x16x32_bf16(vf[d], pf[i], oaccT[d][i], 0, 0, 0);
      __builtin_amdgcn_s_setprio(0);
    }
  };

  // prologue: stage tiles 0,1,2 into slots 0,1,2; certify tile 0; publish
  STAGE(0, 0); STAGE(1, 1); STAGE(2, 2);
  asm volatile("s_waitcnt vmcnt(4)" ::: "memory");   // tile 0's 2 loads done
  __builtin_amdgcn_s_barrier();
  asm volatile("" ::: "memory");

  for (int kt = 0; kt < SEQ / 64; kt++) {
    int st = kt + 3;
    if (st > SEQ / 64 - 1) st = SEQ / 64 - 1;        // clamped dummy re-stage (tail)
    STAGE(st, (kt + 3) & 3);
    const uint16_t* Kb = sm + (kt & 3) * 4096;
    const uint16_t* Vb = sm + 16384 + (kt & 3) * 4096;
    QK_SM(Kb);
    PV(Vb);
    asm volatile("s_waitcnt vmcnt(4)" ::: "memory"); // tile kt+1 loads complete
    __builtin_amdgcn_s_barrier();                    // publish to all waves
    asm volatile("" ::: "memory");
  }

  // final l reduction over the 4 lane-groups holding the same q
#pragma unroll
  for (int i = 0; i < 2; i++) {
    lsum[i] += __shfl_xor(lsum[i], 16, 64);
    lsum[i] += __shfl_xor(lsum[i], 32, 64);
  }
  float rl[2] = {1.f / lsum[0], 1.f / lsum[1]};

  // epilogue: O[q][h*64+d] = O^T/l (RNE), 4 consecutive d per 8B store
#pragma unroll
  for (int i = 0; i < 2; i++) {
    size_t row = (size_t)b * SEQ + q0 + w * 32 + i * 16 + qi;
#pragma unroll
    for (int d = 0; d < 4; d++) {
      uint32_t lo = (uint32_t)f2b(oaccT[d][i][0] * rl[i]) |
                    ((uint32_t)f2b(oaccT[d][i][1] * rl[i]) << 16);
      uint32_t hi = (uint32_t)f2b(oaccT[d][i][2] * rl[i]) |
                    ((uint32_t)f2b(oaccT[d][i][3] * rl[i]) << 16);
      uint2 pk = {lo, hi};
      *(uint2*)(O + row * D_MODEL + h * DKH + d * 16 + g * 4) = pk;
    }
  }
}

extern "C" void kernel_launch(void* const* d_in, const int* in_sizes, int n_in,
                              void* d_out, int out_size, void* d_ws, size_t ws_size,
                              hipStream_t stream) {
  (void)in_sizes; (void)n_in; (void)out_size; (void)ws_size;
  const float* X  = (const float*)d_in[0];
  const float* Wq = (const float*)d_in[1];
  const float* bq = (const float*)d_in[2];
  const float* Wk = (const float*)d_in[3];
  const float* bk = (const float*)d_in[4];
  const float* Wv = (const float*)d_in[5];
  const float* bv = (const float*)d_in[6];
  const float* Wo = (const float*)d_in[7];
  const float* bo = (const float*)d_in[8];
  float* out = (float*)d_out;

  char* p = (char*)d_ws;
  uint16_t* Xb  = (uint16_t*)p; p += (size_t)M_TOK * D_MODEL * 2;
  uint16_t* WqT = (uint16_t*)p; p += (size_t)D_MODEL * D_MODEL * 2;
  uint16_t* WkT = (uint16_t*)p; p += (size_t)D_MODEL * D_MODEL * 2;
  uint16_t* WvT = (uint16_t*)p; p += (size_t)D_MODEL * D_MODEL * 2;
  uint16_t* WoT = (uint16_t*)p; p += (size_t)D_MODEL * D_MODEL * 2;
  uint16_t* Qw  = (uint16_t*)p; p += (size_t)M_TOK * D_MODEL * 2;
  uint16_t* Kw  = (uint16_t*)p; p += (size_t)M_TOK * D_MODEL * 2;
  uint16_t* Vt  = (uint16_t*)p; p += (size_t)M_TOK * D_MODEL * 2;
  uint16_t* Ob  = (uint16_t*)p; p += (size_t)M_TOK * D_MODEL * 2;

  prep<<<6144, 256, 0, stream>>>(X, Xb, Wq, Wk, Wv, Wo, WqT, WkT, WvT, WoT);
  qkv_gemm<<<768, 256, 0, stream>>>(Xb, WqT, WkT, WvT, bq, bk, bv, Qw, Kw, Vt);
  attn_fwd<<<dim3(BATCH * NH, SEQ / 256), 512, 0, stream>>>(Qw, Kw, Vt, Ob);
  oproj_gemm<<<dim3(8, 32), 256, 0, stream>>>(Ob, WoT, bo, out);
}